// Round 1
// baseline (596.269 us; speedup 1.0000x reference)
//
#include <hip/hip_runtime.h>
#include <hip/hip_bf16.h>
#include <math.h>

#define DD   64
#define DD2  128
#define NN   20000
#define RR   24
#define SS   3
#define EE   60000
#define BB   8
#define KK   101
#define HLENN 50

// ---------------------------------------------------------------------------
// degree count: deg[n] += (#src==n) + (#dst==n)
__global__ void deg_kernel(const int* __restrict__ src, const int* __restrict__ dst,
                           int* __restrict__ deg) {
    int i = blockIdx.x * blockDim.x + threadIdx.x;
    if (i < EE) {
        atomicAdd(&deg[src[i]], 1);
        atomicAdd(&deg[dst[i]], 1);
    }
}

// init[n,d] = deg[n]*poi_emb[n,d]; optionally gated with previous output (in x).
// Also writes x = init and zeros agg. 256 threads = 4 nodes x 64 dims.
__global__ void init_kernel(const float* __restrict__ poi_emb, const int* __restrict__ deg,
                            const float* __restrict__ gate_W, const float* __restrict__ gate_b,
                            float* __restrict__ x, float* __restrict__ init,
                            float* __restrict__ agg, int use_gate) {
    __shared__ float sW[64][64];    // 16KB gate_W
    __shared__ float srow[4][64];   // old output rows
    int li = threadIdx.x >> 6;
    int d  = threadIdx.x & 63;
    int node = blockIdx.x * 4 + li;
    if (use_gate) {
        for (int i = threadIdx.x; i < 64 * 64; i += 256) sW[i >> 6][i & 63] = gate_W[i];
    }
    float iv = 0.f, ov = 0.f;
    if (node < NN) {
        iv = (float)deg[node] * poi_emb[node * 64 + d];
        if (use_gate) ov = x[node * 64 + d];
    }
    if (use_gate) {
        srow[li][d] = ov;
        __syncthreads();
        float acc = gate_b[d];
        #pragma unroll
        for (int k = 0; k < 64; ++k) acc += srow[li][k] * sW[k][d];
        float g = 1.f / (1.f + expf(-acc));
        iv = iv * g + (1.f - g) * ov;
    }
    if (node < NN) {
        init[node * 64 + d] = iv;
        x[node * 64 + d]    = iv;
        agg[node * 64 + d]  = 0.f;
    }
}

// msg = x[src] + rel[et]; atomically accumulate into agg[dst]. One wave per edge.
__global__ void scatter_kernel(const float* __restrict__ x, const int* __restrict__ src,
                               const int* __restrict__ dst, const int* __restrict__ et,
                               const float* __restrict__ rel, float* __restrict__ agg) {
    int tid = blockIdx.x * blockDim.x + threadIdx.x;
    int e = tid >> 6;
    int d = tid & 63;
    if (e < EE) {
        int s_ = src[e], dn = dst[e], t_ = et[e];
        float m = x[s_ * 64 + d] + rel[t_ * 64 + d];
        atomicAdd(&agg[dn * 64 + d], m);
    }
}

// x_new = relu([agg, init] @ W + b); also zeros agg for next use.
// W: [128][64] staged in LDS; block processes 32 nodes (8 iters x 4 nodes).
__global__ void gnn_linear_kernel(const float* __restrict__ agg_in,
                                  const float* __restrict__ initb,
                                  const float* __restrict__ W,
                                  const float* __restrict__ bvec,
                                  float* __restrict__ x,
                                  float* __restrict__ agg_clear) {
    __shared__ float sW[128][64];   // 32KB
    __shared__ float srow[4][128];
    for (int i = threadIdx.x; i < 128 * 64; i += 256) sW[i >> 6][i & 63] = W[i];
    int li = threadIdx.x >> 6;
    int d  = threadIdx.x & 63;
    float bb = bvec[d];
    __syncthreads();
    for (int it = 0; it < 8; ++it) {
        int node = blockIdx.x * 32 + it * 4 + li;
        float a0 = 0.f, i0 = 0.f;
        if (node < NN) { a0 = agg_in[node * 64 + d]; i0 = initb[node * 64 + d]; }
        srow[li][d] = a0;
        srow[li][64 + d] = i0;
        __syncthreads();
        float acc = bb;
        #pragma unroll
        for (int k = 0; k < 128; ++k) acc += srow[li][k] * sW[k][d];
        if (node < NN) {
            x[node * 64 + d] = fmaxf(acc, 0.f);
            agg_clear[node * 64 + d] = 0.f;
        }
        __syncthreads();
    }
}

// query[b] = query_emb[r_index[b]] run through 3x ((q+time)@g_lin_W + b). 1 block, 512 thr.
__global__ void query_kernel(const float* __restrict__ query_emb, const int* __restrict__ r_index,
                             const float* __restrict__ g_time_emb, const int* __restrict__ g_time,
                             const float* __restrict__ g_lin_W, const float* __restrict__ g_lin_b,
                             float* __restrict__ query) {
    __shared__ float sW[64][64];
    __shared__ float sq[8][64];
    int b = threadIdx.x >> 6;
    int d = threadIdx.x & 63;
    for (int i = threadIdx.x; i < 64 * 64; i += 512) sW[i >> 6][i & 63] = g_lin_W[i];
    float q = query_emb[r_index[b] * 64 + d];
    for (int s = 0; s < SS; ++s) {
        float t = q + g_time_emb[g_time[s] * 64 + d];
        sq[b][d] = t;
        __syncthreads();
        float acc = g_lin_b[d];
        #pragma unroll
        for (int k = 0; k < 64; ++k) acc += sq[b][k] * sW[k][d];
        q = acc;
        __syncthreads();
    }
    query[b * 64 + d] = q;
}

// xseq[b,t,:] = concat(feature[history_poi[b,t]], query[b]) + hte[b,t,:]
__global__ void xseq_kernel(const float* __restrict__ feature, const float* __restrict__ query,
                            const int* __restrict__ history_poi, const float* __restrict__ hte,
                            float* __restrict__ xseq) {
    int idx = blockIdx.x * 256 + threadIdx.x;
    if (idx >= BB * HLENN * DD2) return;
    int c = idx & 127;
    int bt = idx >> 7;
    int b = bt / HLENN, t = bt % HLENN;
    float v = (c < 64) ? feature[history_poi[b * HLENN + t] * 64 + c]
                       : query[b * 64 + (c - 64)];
    xseq[idx] = v + hte[idx];
}

// Generic row GEMM: C[row] = act(A[row] @ W + bias). blockIdx = row, thread = col.
template<int KDIM, int NC, bool RELU>
__global__ void rowmm_kernel(const float* __restrict__ A, const float* __restrict__ W,
                             const float* __restrict__ bias, float* __restrict__ Cout) {
    __shared__ float srow[KDIM];
    int row = blockIdx.x;
    for (int i = threadIdx.x; i < KDIM; i += blockDim.x) srow[i] = A[row * KDIM + i];
    __syncthreads();
    for (int col = threadIdx.x; col < NC; col += blockDim.x) {
        float acc = bias ? bias[col] : 0.f;
        #pragma unroll 8
        for (int k = 0; k < KDIM; ++k) acc += srow[k] * W[k * NC + col];
        Cout[row * NC + col] = RELU ? fmaxf(acc, 0.f) : acc;
    }
}

// attention per (b, head): 16 blocks, 256 threads.
__global__ void attn_kernel(const float* __restrict__ qkv, float* __restrict__ attnout) {
    int b = blockIdx.x >> 1, h = blockIdx.x & 1;
    __shared__ float sq[HLENN][64], sk[HLENN][64], sv[HLENN][64];
    __shared__ float ss[HLENN][HLENN];
    for (int i = threadIdx.x; i < HLENN * 64; i += 256) {
        int t = i >> 6, d = i & 63;
        const float* base = qkv + (size_t)(b * HLENN + t) * 384 + h * 64 + d;
        sq[t][d] = base[0];
        sk[t][d] = base[128];
        sv[t][d] = base[256];
    }
    __syncthreads();
    for (int p = threadIdx.x; p < HLENN * HLENN; p += 256) {
        int i = p / HLENN, j = p % HLENN;
        float acc = 0.f;
        #pragma unroll 8
        for (int d = 0; d < 64; ++d) acc += sq[i][d] * sk[j][d];
        ss[i][j] = acc * 0.125f; // 1/sqrt(64)
    }
    __syncthreads();
    if (threadIdx.x < HLENN) {
        int i = threadIdx.x;
        float m = -1e30f;
        for (int j = 0; j < HLENN; ++j) m = fmaxf(m, ss[i][j]);
        float sum = 0.f;
        for (int j = 0; j < HLENN; ++j) { float e = expf(ss[i][j] - m); ss[i][j] = e; sum += e; }
        float inv = 1.f / sum;
        for (int j = 0; j < HLENN; ++j) ss[i][j] *= inv;
    }
    __syncthreads();
    for (int p = threadIdx.x; p < HLENN * 64; p += 256) {
        int i = p >> 6, d = p & 63;
        float acc = 0.f;
        for (int j = 0; j < HLENN; ++j) acc += ss[i][j] * sv[j][d];
        attnout[(size_t)(b * HLENN + i) * 128 + h * 64 + d] = acc;
    }
}

// out[row] = LayerNorm(resid[row] + A[row] @ W + bias). 128 threads per row-block.
template<int KDIM>
__global__ void addLN_kernel(const float* __restrict__ Ain, const float* __restrict__ W,
                             const float* __restrict__ bias, const float* __restrict__ resid,
                             const float* __restrict__ ln,  // [scale(128), bias(128)]
                             float* __restrict__ out) {
    __shared__ float srow[KDIM];
    __shared__ float sred[128];
    int row = blockIdx.x;
    int col = threadIdx.x;
    for (int i = col; i < KDIM; i += 128) srow[i] = Ain[row * KDIM + i];
    __syncthreads();
    float acc = bias ? bias[col] : 0.f;
    #pragma unroll 8
    for (int k = 0; k < KDIM; ++k) acc += srow[k] * W[k * 128 + col];
    acc += resid[row * 128 + col];
    float xv = acc;
    sred[col] = xv;
    __syncthreads();
    for (int off = 64; off > 0; off >>= 1) { if (col < off) sred[col] += sred[col + off]; __syncthreads(); }
    float mean = sred[0] * (1.f / 128.f);
    __syncthreads();
    float dx = xv - mean;
    sred[col] = dx * dx;
    __syncthreads();
    for (int off = 64; off > 0; off >>= 1) { if (col < off) sred[col] += sred[col + off]; __syncthreads(); }
    float var = sred[0] * (1.f / 128.f);
    out[row * 128 + col] = dx * rsqrtf(var + 1e-5f) * ln[col] + ln[128 + col];
}

__global__ void mean_kernel(const float* __restrict__ xseq, float* __restrict__ flabel) {
    int i = blockIdx.x * 256 + threadIdx.x;
    if (i >= BB * 128) return;
    int b = i >> 7, c = i & 127;
    float s = 0.f;
    for (int t = 0; t < HLENN; ++t) s += xseq[(b * HLENN + t) * 128 + c];
    flabel[i] = s * (1.f / HLENN);
}

// score[b,k] = relu([feature[t_index], flabel[b]] @ W1 + b1) @ W2 + b2. 192 threads/block.
__global__ void score_kernel(const float* __restrict__ feature, const float* __restrict__ flabel,
                             const int* __restrict__ t_index,
                             const float* __restrict__ W1, const float* __restrict__ b1,
                             const float* __restrict__ W2, const float* __restrict__ b2,
                             float* __restrict__ score) {
    int b = blockIdx.x / KK, k = blockIdx.x % KK;
    __shared__ float sf[192];
    __shared__ float sred[192];
    int j = threadIdx.x;
    int t = t_index[b * KK + k];
    sf[j] = (j < 64) ? feature[t * 64 + j] : flabel[b * 128 + (j - 64)];
    __syncthreads();
    float acc = b1[j];
    #pragma unroll 8
    for (int i = 0; i < 192; ++i) acc += sf[i] * W1[i * 192 + j];
    float h = fmaxf(acc, 0.f);
    sred[j] = h * W2[j];
    __syncthreads();
    if (j < 64) sred[j] += sred[j + 64] + sred[j + 128];
    __syncthreads();
    for (int off = 32; off > 0; off >>= 1) { if (j < off) sred[j] += sred[j + off]; __syncthreads(); }
    if (j == 0) score[b * KK + k] = sred[0] + b2[0];
}

// ---------------------------------------------------------------------------
extern "C" void kernel_launch(void* const* d_in, const int* in_sizes, int n_in,
                              void* d_out, int out_size, void* d_ws, size_t ws_size,
                              hipStream_t stream) {
    const float* poi_emb   = (const float*)d_in[0];   // [N,64]
    const float* query_emb = (const float*)d_in[1];   // [24,64]
    const float* gate_W    = (const float*)d_in[2];   // [64,64]
    const float* gate_b    = (const float*)d_in[3];   // [64]
    const float* gnn_rel   = (const float*)d_in[4];   // [2,24,64]
    const float* gnn_W     = (const float*)d_in[5];   // [2,128,64]
    const float* gnn_b     = (const float*)d_in[6];   // [2,64]
    const float* g_time_emb= (const float*)d_in[7];   // [48,64]
    const float* g_lin_W   = (const float*)d_in[8];   // [64,64]
    const float* g_lin_b   = (const float*)d_in[9];   // [64]
    const float* tf_Wqkv   = (const float*)d_in[10];  // [2,128,384]
    const float* tf_Wo     = (const float*)d_in[11];  // [2,128,128]
    const float* tf_ln1    = (const float*)d_in[12];  // [2,2,128]
    const float* tf_ln2    = (const float*)d_in[13];  // [2,2,128]
    const float* tf_W1     = (const float*)d_in[14];  // [2,128,512]
    const float* tf_b1     = (const float*)d_in[15];  // [2,512]
    const float* tf_W2     = (const float*)d_in[16];  // [2,512,128]
    const float* tf_b2     = (const float*)d_in[17];  // [2,128]
    const float* mlp_W1    = (const float*)d_in[18];  // [192,192]
    const float* mlp_b1    = (const float*)d_in[19];  // [192]
    const float* mlp_W2    = (const float*)d_in[20];  // [192,1]
    const float* mlp_b2    = (const float*)d_in[21];  // [1]
    const float* hte       = (const float*)d_in[22];  // [8,50,128]
    const int* edge_src    = (const int*)d_in[23];    // [3,60000]
    const int* edge_dst    = (const int*)d_in[24];
    const int* edge_type   = (const int*)d_in[25];
    const int* r_index     = (const int*)d_in[27];    // [8]  (h_index at 26 is unused)
    const int* t_index     = (const int*)d_in[28];    // [8,101]
    const int* history_poi = (const int*)d_in[29];    // [8,50]
    const int* g_time      = (const int*)d_in[30];    // [3]

    float* ws = (float*)d_ws;
    float* x     = ws;                    // N*64
    float* initb = x     + NN * 64;       // N*64
    float* agg   = initb + NN * 64;       // N*64
    float* query = agg   + NN * 64;       // 512
    float* xseq  = query + 512;           // 8*50*128
    float* qkvb  = xseq  + BB * HLENN * 128;   // 8*50*384
    float* aout  = qkvb  + BB * HLENN * 384;   // 8*50*128
    float* h1    = aout  + BB * HLENN * 128;   // 8*50*512
    float* flab  = h1    + BB * HLENN * 512;   // 8*128
    int*   deg   = (int*)(flab + BB * 128);    // N ints

    // ---- GNN over snapshots (batch-independent: computed once, not 8x) ----
    for (int s = 0; s < SS; ++s) {
        hipMemsetAsync(deg, 0, NN * sizeof(int), stream);
        deg_kernel<<<(EE + 255) / 256, 256, 0, stream>>>(edge_src + s * EE, edge_dst + s * EE, deg);
        init_kernel<<<(NN + 3) / 4, 256, 0, stream>>>(poi_emb, deg, gate_W, gate_b,
                                                      x, initb, agg, s > 0 ? 1 : 0);
        for (int l = 0; l < 2; ++l) {
            scatter_kernel<<<(EE * 64) / 256, 256, 0, stream>>>(
                x, edge_src + s * EE, edge_dst + s * EE, edge_type + s * EE,
                gnn_rel + l * RR * 64, agg);
            gnn_linear_kernel<<<(NN + 31) / 32, 256, 0, stream>>>(
                agg, initb, gnn_W + l * 128 * 64, gnn_b + l * 64, x, agg);
        }
    }

    // ---- query path ----
    query_kernel<<<1, 512, 0, stream>>>(query_emb, r_index, g_time_emb, g_time,
                                        g_lin_W, g_lin_b, query);
    xseq_kernel<<<(BB * HLENN * 128 + 255) / 256, 256, 0, stream>>>(x, query, history_poi, hte, xseq);

    // ---- transformer (2 layers on [8,50,128]) ----
    for (int l = 0; l < 2; ++l) {
        rowmm_kernel<128, 384, false><<<BB * HLENN, 384, 0, stream>>>(
            xseq, tf_Wqkv + l * 128 * 384, nullptr, qkvb);
        attn_kernel<<<BB * 2, 256, 0, stream>>>(qkvb, aout);
        addLN_kernel<128><<<BB * HLENN, 128, 0, stream>>>(
            aout, tf_Wo + l * 128 * 128, nullptr, xseq, tf_ln1 + l * 256, xseq);
        rowmm_kernel<128, 512, true><<<BB * HLENN, 512, 0, stream>>>(
            xseq, tf_W1 + l * 128 * 512, tf_b1 + l * 512, h1);
        addLN_kernel<512><<<BB * HLENN, 128, 0, stream>>>(
            h1, tf_W2 + l * 512 * 128, tf_b2 + l * 128, xseq, tf_ln2 + l * 256, xseq);
    }

    // ---- scoring ----
    mean_kernel<<<(BB * 128 + 255) / 256, 256, 0, stream>>>(xseq, flab);
    score_kernel<<<BB * KK, 192, 0, stream>>>(x, flab, t_index,
                                              mlp_W1, mlp_b1, mlp_W2, mlp_b2, (float*)d_out);
}

// Round 4
// 526.041 us; speedup vs baseline: 1.1335x; 1.1335x over previous
//
#include <hip/hip_runtime.h>
#include <hip/hip_bf16.h>
#include <math.h>

#define DD   64
#define DD2  128
#define NN   20000
#define RR   24
#define SS   3
#define EE   60000
#define BB   8
#define KK   101
#define HLENN 50
#define MROWS 20024   // 20000 nodes + 24 appended rel rows

// ---------------------------------------------------------------------------
// histogram by dst (for CSR) + full degree (src+dst counts)
__global__ void hist_kernel(const int* __restrict__ src, const int* __restrict__ dst,
                            int* __restrict__ hist, int* __restrict__ deg) {
    int s = blockIdx.y;
    int e = blockIdx.x * 256 + threadIdx.x;
    if (e < EE) {
        int d0 = dst[s * EE + e], s0 = src[s * EE + e];
        atomicAdd(&hist[s * NN + d0], 1);
        atomicAdd(&deg[s * NN + d0], 1);
        atomicAdd(&deg[s * NN + s0], 1);
    }
}

// exclusive scan of hist -> rowptr (N+1) and cursor copy. One block per snapshot.
__global__ void scan_kernel(const int* __restrict__ hist, int* __restrict__ rowptr,
                            int* __restrict__ cursor) {
    int s = blockIdx.x, t = threadIdx.x;
    const int* h = hist + s * NN;
    int* rp = rowptr + s * (NN + 1);
    int* cur = cursor + s * NN;
    __shared__ int sp[1024];
    int base = t * 20, sum = 0;
    for (int i = 0; i < 20; ++i) { int idx = base + i; if (idx < NN) sum += h[idx]; }
    sp[t] = sum;
    __syncthreads();
    for (int off = 1; off < 1024; off <<= 1) {
        int v = (t >= off) ? sp[t - off] : 0;
        __syncthreads();
        sp[t] += v;
        __syncthreads();
    }
    int run = sp[t] - sum;  // exclusive
    for (int i = 0; i < 20; ++i) {
        int idx = base + i;
        if (idx < NN) { rp[idx] = run; cur[idx] = run; run += h[idx]; }
    }
    if (t == 1023) rp[NN] = sp[1023];
}

// place edges into CSR slots: col[pos] = src | (et<<16)
__global__ void place_kernel(const int* __restrict__ src, const int* __restrict__ dst,
                             const int* __restrict__ et, int* __restrict__ cursor,
                             int* __restrict__ colp) {
    int s = blockIdx.y;
    int e = blockIdx.x * 256 + threadIdx.x;
    if (e < EE) {
        int d0 = dst[s * EE + e];
        int pos = atomicAdd(&cursor[s * NN + d0], 1);
        colp[s * EE + pos] = src[s * EE + e] | (et[s * EE + e] << 16);
    }
}

// init[n,d] = deg[n]*poi[n,d], gated against previous output for s>0.
__global__ void init_kernel(const float* __restrict__ poi, const int* __restrict__ deg,
                            const float* __restrict__ gate_W, const float* __restrict__ gate_b,
                            const float* __restrict__ xprev, float* __restrict__ initb,
                            int use_gate) {
    __shared__ float sW[64][64];
    __shared__ float srow[4][64];
    int li = threadIdx.x >> 6, d = threadIdx.x & 63;
    int node = blockIdx.x * 4 + li;   // 5000 blocks * 4 = 20000 exact
    if (use_gate) {
        for (int i = threadIdx.x; i < 64 * 64; i += 256) sW[i >> 6][i & 63] = gate_W[i];
    }
    float iv = (float)deg[node] * poi[node * 64 + d];
    if (use_gate) {
        float ov = xprev[node * 64 + d];
        srow[li][d] = ov;
        __syncthreads();
        float acc = gate_b[d];
        #pragma unroll
        for (int k = 0; k < 64; ++k) acc += srow[li][k] * sW[k][d];
        float g = 1.f / (1.f + expf(-acc));
        iv = iv * g + (1.f - g) * ov;
    }
    initb[node * 64 + d] = iv;
}

// batched C = A @ B, A: [20024 x 64] (rows >=20000 from Ar), B: [64 x 64], C: [.. x 64]
// 64x64 tile per block, 256 threads, 4x4 micro-tile.
__global__ void gemm64_kernel(const float* __restrict__ A0a, const float* __restrict__ Ar_a,
                              const float* __restrict__ Ba, float* __restrict__ Ca,
                              const float* __restrict__ A0b, const float* __restrict__ Ar_b,
                              const float* __restrict__ Bb, float* __restrict__ Cb) {
    const float* A0 = blockIdx.y ? A0b : A0a;
    const float* Ar = blockIdx.y ? Ar_b : Ar_a;
    const float* B  = blockIdx.y ? Bb  : Ba;
    float* C        = blockIdx.y ? Cb  : Ca;
    __shared__ float sA[64][68];
    __shared__ float sB[64][68];
    int tid = threadIdx.x;
    int row0 = blockIdx.x * 64;
    for (int i = tid; i < 64 * 16; i += 256) {
        int r = i >> 4, cq = i & 15;
        int row = row0 + r;
        float4 v = make_float4(0.f, 0.f, 0.f, 0.f);
        if (row < NN)        v = *(const float4*)(A0 + (size_t)row * 64 + cq * 4);
        else if (row < MROWS) v = *(const float4*)(Ar + (size_t)(row - NN) * 64 + cq * 4);
        *(float4*)&sA[r][cq * 4] = v;
        if (i < 64 * 16) {
            // stage B (64x64) with the same index space (r = k)
            float4 w = *(const float4*)(B + (size_t)r * 64 + cq * 4);
            *(float4*)&sB[r][cq * 4] = w;
        }
    }
    __syncthreads();
    int tr = tid >> 4, tc = tid & 15;
    float acc[4][4] = {{0.f}};
    #pragma unroll 16
    for (int k = 0; k < 64; ++k) {
        float4 b4 = *(const float4*)&sB[k][tc * 4];
        float a0 = sA[tr * 4 + 0][k];
        float a1 = sA[tr * 4 + 1][k];
        float a2 = sA[tr * 4 + 2][k];
        float a3 = sA[tr * 4 + 3][k];
        acc[0][0] += a0 * b4.x; acc[0][1] += a0 * b4.y; acc[0][2] += a0 * b4.z; acc[0][3] += a0 * b4.w;
        acc[1][0] += a1 * b4.x; acc[1][1] += a1 * b4.y; acc[1][2] += a1 * b4.z; acc[1][3] += a1 * b4.w;
        acc[2][0] += a2 * b4.x; acc[2][1] += a2 * b4.y; acc[2][2] += a2 * b4.z; acc[2][3] += a2 * b4.w;
        acc[3][0] += a3 * b4.x; acc[3][1] += a3 * b4.y; acc[3][2] += a3 * b4.z; acc[3][3] += a3 * b4.w;
    }
    #pragma unroll
    for (int i = 0; i < 4; ++i) {
        int row = row0 + tr * 4 + i;
        if (row < MROWS) {
            float4 o = make_float4(acc[i][0], acc[i][1], acc[i][2], acc[i][3]);
            *(float4*)(C + (size_t)row * 64 + tc * 4) = o;
        }
    }
}

// x_out[n] = relu( z[n] + b + sum_{e in-edges(n)} ( y[src_e] + relW[et_e] ) )
// relW = y rows 20000..20023 (staged in LDS).
__global__ void fin_kernel(const float* __restrict__ y, const float* __restrict__ z,
                           const int* __restrict__ rowptr, const int* __restrict__ colp,
                           const float* __restrict__ bias, float* __restrict__ xout) {
    __shared__ float srelW[24][64];
    int tid = threadIdx.x;
    for (int i = tid; i < 24 * 64; i += 256) srelW[i >> 6][i & 63] = y[NN * 64 + i];
    int d = tid & 63, w = tid >> 6;
    float bb = bias[d];
    __syncthreads();
    int base = blockIdx.x * 16 + w * 4;   // 1250 blocks * 16 = 20000 exact
    for (int n = 0; n < 4; ++n) {
        int node = base + n;
        float acc = z[node * 64 + d] + bb;
        int e0 = rowptr[node], e1 = rowptr[node + 1];
        for (int e = e0; e < e1; ++e) {
            int pack = colp[e];
            acc += y[(size_t)(pack & 0xFFFF) * 64 + d] + srelW[pack >> 16][d];
        }
        xout[node * 64 + d] = fmaxf(acc, 0.f);
    }
}

// query[b] = query_emb[r_index[b]] through 3x ((q + time) @ g_lin_W + b)
__global__ void query_kernel(const float* __restrict__ query_emb, const int* __restrict__ r_index,
                             const float* __restrict__ g_time_emb, const int* __restrict__ g_time,
                             const float* __restrict__ g_lin_W, const float* __restrict__ g_lin_b,
                             float* __restrict__ query) {
    __shared__ float sW[64][64];
    __shared__ float sq[8][64];
    int b = threadIdx.x >> 6;
    int d = threadIdx.x & 63;
    for (int i = threadIdx.x; i < 64 * 64; i += 512) sW[i >> 6][i & 63] = g_lin_W[i];
    float q = query_emb[r_index[b] * 64 + d];
    for (int s = 0; s < SS; ++s) {
        float t = q + g_time_emb[g_time[s] * 64 + d];
        sq[b][d] = t;
        __syncthreads();
        float acc = g_lin_b[d];
        #pragma unroll
        for (int k = 0; k < 64; ++k) acc += sq[b][k] * sW[k][d];
        q = acc;
        __syncthreads();
    }
    query[b * 64 + d] = q;
}

__global__ void xseq_kernel(const float* __restrict__ feature, const float* __restrict__ query,
                            const int* __restrict__ history_poi, const float* __restrict__ hte,
                            float* __restrict__ xseq) {
    int idx = blockIdx.x * 256 + threadIdx.x;
    if (idx >= BB * HLENN * DD2) return;
    int c = idx & 127;
    int bt = idx >> 7;
    int b = bt / HLENN, t = bt % HLENN;
    float v = (c < 64) ? feature[history_poi[b * HLENN + t] * 64 + c]
                       : query[b * 64 + (c - 64)];
    xseq[idx] = v + hte[idx];
}

// qkv for 4 rows per block; 384 threads (thread = output col)
__global__ void qkv4_kernel(const float* __restrict__ xseq, const float* __restrict__ Wqkv,
                            float* __restrict__ qkvb) {
    __shared__ float sx[4][128];
    int tid = threadIdx.x;
    int row0 = blockIdx.x * 4;
    for (int i = tid; i < 512; i += 384) sx[i >> 7][i & 127] = xseq[row0 * 128 + i];
    __syncthreads();
    float a0 = 0.f, a1 = 0.f, a2 = 0.f, a3 = 0.f;
    #pragma unroll 8
    for (int k = 0; k < 128; ++k) {
        float w = Wqkv[k * 384 + tid];
        a0 += sx[0][k] * w; a1 += sx[1][k] * w; a2 += sx[2][k] * w; a3 += sx[3][k] * w;
    }
    qkvb[(row0 + 0) * 384 + tid] = a0;
    qkvb[(row0 + 1) * 384 + tid] = a1;
    qkvb[(row0 + 2) * 384 + tid] = a2;
    qkvb[(row0 + 3) * 384 + tid] = a3;
}

// attention per (b, head): 16 blocks, 256 threads
__global__ void attn_kernel(const float* __restrict__ qkv, float* __restrict__ attnout) {
    int b = blockIdx.x >> 1, h = blockIdx.x & 1;
    __shared__ float sq[HLENN][64], sk[HLENN][64], sv[HLENN][64];
    __shared__ float ss[HLENN][HLENN];
    for (int i = threadIdx.x; i < HLENN * 64; i += 256) {
        int t = i >> 6, d = i & 63;
        const float* base = qkv + (size_t)(b * HLENN + t) * 384 + h * 64 + d;
        sq[t][d] = base[0];
        sk[t][d] = base[128];
        sv[t][d] = base[256];
    }
    __syncthreads();
    for (int p = threadIdx.x; p < HLENN * HLENN; p += 256) {
        int i = p / HLENN, j = p % HLENN;
        float acc = 0.f;
        #pragma unroll 8
        for (int d = 0; d < 64; ++d) acc += sq[i][d] * sk[j][d];
        ss[i][j] = acc * 0.125f;
    }
    __syncthreads();
    if (threadIdx.x < HLENN) {
        int i = threadIdx.x;
        float m = -1e30f;
        for (int j = 0; j < HLENN; ++j) m = fmaxf(m, ss[i][j]);
        float sum = 0.f;
        for (int j = 0; j < HLENN; ++j) { float e = expf(ss[i][j] - m); ss[i][j] = e; sum += e; }
        float inv = 1.f / sum;
        for (int j = 0; j < HLENN; ++j) ss[i][j] *= inv;
    }
    __syncthreads();
    for (int p = threadIdx.x; p < HLENN * 64; p += 256) {
        int i = p >> 6, d = p & 63;
        float acc = 0.f;
        for (int j = 0; j < HLENN; ++j) acc += ss[i][j] * sv[j][d];
        attnout[(size_t)(b * HLENN + i) * 128 + h * 64 + d] = acc;
    }
}

// out = LN(resid + aout @ Wo), 4 rows/block, 512 threads
__global__ void addLN4_kernel(const float* __restrict__ aout, const float* __restrict__ Wo,
                              const float* __restrict__ ln, float* __restrict__ xseq) {
    __shared__ float sa[4][128];
    __shared__ float sred[4][128];
    int tid = threadIdx.x;
    int r = tid >> 7, c = tid & 127;
    int row0 = blockIdx.x * 4;
    sa[r][c] = aout[(row0 + r) * 128 + c];
    __syncthreads();
    float acc = xseq[(row0 + r) * 128 + c];
    #pragma unroll 8
    for (int k = 0; k < 128; ++k) acc += sa[r][k] * Wo[k * 128 + c];
    sred[r][c] = acc; __syncthreads();
    for (int off = 64; off > 0; off >>= 1) { if (c < off) sred[r][c] += sred[r][c + off]; __syncthreads(); }
    float mean = sred[r][0] * (1.f / 128.f);
    __syncthreads();
    float dx = acc - mean;
    sred[r][c] = dx * dx; __syncthreads();
    for (int off = 64; off > 0; off >>= 1) { if (c < off) sred[r][c] += sred[r][c + off]; __syncthreads(); }
    float var = sred[r][0] * (1.f / 128.f);
    xseq[(row0 + r) * 128 + c] = dx * rsqrtf(var + 1e-5f) * ln[c] + ln[128 + c];
}

// fused ff1 + relu + ff2 + residual + LN, 4 rows/block, 512 threads
__global__ void ffLN4_kernel(const float* __restrict__ xin, const float* __restrict__ W1,
                             const float* __restrict__ b1, const float* __restrict__ W2,
                             const float* __restrict__ b2, const float* __restrict__ ln,
                             float* __restrict__ xout) {
    __shared__ float sx[4][128];
    __shared__ float sh[4][512];
    __shared__ float spart[4][4][128];
    __shared__ float sred[4][128];
    int tid = threadIdx.x;
    int row0 = blockIdx.x * 4;
    { int r = tid >> 7, c = tid & 127; sx[r][c] = xin[(row0 + r) * 128 + c]; }
    __syncthreads();
    {
        float bb = b1[tid];
        float a0 = bb, a1 = bb, a2 = bb, a3 = bb;
        #pragma unroll 8
        for (int k = 0; k < 128; ++k) {
            float w = W1[k * 512 + tid];
            a0 += sx[0][k] * w; a1 += sx[1][k] * w; a2 += sx[2][k] * w; a3 += sx[3][k] * w;
        }
        sh[0][tid] = fmaxf(a0, 0.f); sh[1][tid] = fmaxf(a1, 0.f);
        sh[2][tid] = fmaxf(a2, 0.f); sh[3][tid] = fmaxf(a3, 0.f);
    }
    __syncthreads();
    int kc = tid >> 7, c = tid & 127;
    float p0 = 0.f, p1 = 0.f, p2 = 0.f, p3 = 0.f;
    #pragma unroll 8
    for (int kk = 0; kk < 128; ++kk) {
        int k = kc * 128 + kk;
        float w = W2[k * 128 + c];
        p0 += sh[0][k] * w; p1 += sh[1][k] * w; p2 += sh[2][k] * w; p3 += sh[3][k] * w;
    }
    spart[kc][0][c] = p0; spart[kc][1][c] = p1; spart[kc][2][c] = p2; spart[kc][3][c] = p3;
    __syncthreads();
    int r = kc;
    float acc = b2[c] + spart[0][r][c] + spart[1][r][c] + spart[2][r][c] + spart[3][r][c] + sx[r][c];
    sred[r][c] = acc; __syncthreads();
    for (int off = 64; off > 0; off >>= 1) { if (c < off) sred[r][c] += sred[r][c + off]; __syncthreads(); }
    float mean = sred[r][0] * (1.f / 128.f);
    __syncthreads();
    float dx = acc - mean;
    sred[r][c] = dx * dx; __syncthreads();
    for (int off = 64; off > 0; off >>= 1) { if (c < off) sred[r][c] += sred[r][c + off]; __syncthreads(); }
    float var = sred[r][0] * (1.f / 128.f);
    xout[(row0 + r) * 128 + c] = dx * rsqrtf(var + 1e-5f) * ln[c] + ln[128 + c];
}

__global__ void mean_kernel(const float* __restrict__ xseq, float* __restrict__ flabel) {
    int i = blockIdx.x * 256 + threadIdx.x;
    if (i >= BB * 128) return;
    int b = i >> 7, c = i & 127;
    float s = 0.f;
    for (int t = 0; t < HLENN; ++t) s += xseq[(b * HLENN + t) * 128 + c];
    flabel[i] = s * (1.f / HLENN);
}

__global__ void score_kernel(const float* __restrict__ feature, const float* __restrict__ flabel,
                             const int* __restrict__ t_index,
                             const float* __restrict__ W1, const float* __restrict__ b1,
                             const float* __restrict__ W2, const float* __restrict__ b2,
                             float* __restrict__ score) {
    int b = blockIdx.x / KK, k = blockIdx.x % KK;
    __shared__ float sf[192];
    __shared__ float sred[192];
    int j = threadIdx.x;
    int t = t_index[b * KK + k];
    sf[j] = (j < 64) ? feature[t * 64 + j] : flabel[b * 128 + (j - 64)];
    __syncthreads();
    float acc = b1[j];
    #pragma unroll 8
    for (int i = 0; i < 192; ++i) acc += sf[i] * W1[i * 192 + j];
    float h = fmaxf(acc, 0.f);
    sred[j] = h * W2[j];
    __syncthreads();
    if (j < 64) sred[j] += sred[j + 64] + sred[j + 128];
    __syncthreads();
    for (int off = 32; off > 0; off >>= 1) { if (j < off) sred[j] += sred[j + off]; __syncthreads(); }
    if (j == 0) score[b * KK + k] = sred[0] + b2[0];
}

// ---------------------------------------------------------------------------
extern "C" void kernel_launch(void* const* d_in, const int* in_sizes, int n_in,
                              void* d_out, int out_size, void* d_ws, size_t ws_size,
                              hipStream_t stream) {
    const float* poi_emb   = (const float*)d_in[0];
    const float* query_emb = (const float*)d_in[1];
    const float* gate_W    = (const float*)d_in[2];
    const float* gate_b    = (const float*)d_in[3];
    const float* gnn_rel   = (const float*)d_in[4];   // [2,24,64]
    const float* gnn_W     = (const float*)d_in[5];   // [2,128,64]
    const float* gnn_b     = (const float*)d_in[6];   // [2,64]
    const float* g_time_emb= (const float*)d_in[7];
    const float* g_lin_W   = (const float*)d_in[8];
    const float* g_lin_b   = (const float*)d_in[9];
    const float* tf_Wqkv   = (const float*)d_in[10];
    const float* tf_Wo     = (const float*)d_in[11];
    const float* tf_ln1    = (const float*)d_in[12];
    const float* tf_ln2    = (const float*)d_in[13];
    const float* tf_W1     = (const float*)d_in[14];
    const float* tf_b1     = (const float*)d_in[15];
    const float* tf_W2     = (const float*)d_in[16];
    const float* tf_b2     = (const float*)d_in[17];
    const float* mlp_W1    = (const float*)d_in[18];
    const float* mlp_b1    = (const float*)d_in[19];
    const float* mlp_W2    = (const float*)d_in[20];
    const float* mlp_b2    = (const float*)d_in[21];
    const float* hte       = (const float*)d_in[22];
    const int* edge_src    = (const int*)d_in[23];
    const int* edge_dst    = (const int*)d_in[24];
    const int* edge_type   = (const int*)d_in[25];
    const int* r_index     = (const int*)d_in[27];
    const int* t_index     = (const int*)d_in[28];
    const int* history_poi = (const int*)d_in[29];
    const int* g_time      = (const int*)d_in[30];

    float* ws = (float*)d_ws;
    float* xA    = ws;                         // 1,280,000
    float* xB    = xA + 1280000;
    float* initb = xB + 1280000;
    float* y     = initb + 1280000;            // 20032*64
    float* z     = y + 20032 * 64;
    float* query = z + 20032 * 64;             // 512
    float* xseq  = query + 512;                // 51200
    float* qkvb  = xseq + 51200;               // 153600
    float* aout  = qkvb + 153600;              // 51200
    float* flab  = aout + 51200;               // 1024
    int* hist    = (int*)(flab + 1024);        // 3*NN
    int* deg     = hist + 3 * NN;              // 3*NN
    int* rowptr  = deg + 3 * NN;               // 3*(NN+1)
    int* cursor  = rowptr + 3 * (NN + 1);      // 3*NN
    int* colp    = cursor + 3 * NN;            // 3*EE

    // ---- CSR build + degree for all 3 snapshots at once ----
    hipMemsetAsync(hist, 0, 2 * 3 * NN * sizeof(int), stream);   // hist + deg contiguous
    {
        dim3 g((EE + 255) / 256, 3);
        hist_kernel<<<g, 256, 0, stream>>>(edge_src, edge_dst, hist, deg);
        scan_kernel<<<3, 1024, 0, stream>>>(hist, rowptr, cursor);
        place_kernel<<<g, 256, 0, stream>>>(edge_src, edge_dst, edge_type, cursor, colp);
    }

    // ---- GNN over snapshots (batch-independent) ----
    for (int s = 0; s < SS; ++s) {
        const int* rp = rowptr + s * (NN + 1);
        const int* cp = colp + s * EE;
        init_kernel<<<NN / 4, 256, 0, stream>>>(poi_emb, deg + s * NN, gate_W, gate_b,
                                                xA, initb, s > 0 ? 1 : 0);
        const float* Wt0 = gnn_W;                 // layer0 rows 0..63 (agg part)
        const float* Wb0 = gnn_W + 64 * 64;       // layer0 rows 64..127 (init part)
        const float* Wt1 = gnn_W + 128 * 64;
        const float* Wb1 = gnn_W + 128 * 64 + 64 * 64;
        const float* rel0 = gnn_rel;
        const float* rel1 = gnn_rel + 24 * 64;
        dim3 gg(313, 2);
        // layer 0:  y = init@Wt0 (+rel0 rows),  z = init@Wb0
        gemm64_kernel<<<gg, 256, 0, stream>>>(initb, rel0, Wt0, y,
                                              initb, rel0, Wb0, z);
        fin_kernel<<<NN / 16, 256, 0, stream>>>(y, z, rp, cp, gnn_b, xB);
        // layer 1:  y = x1@Wt1 (+rel1 rows),  z = init@Wb1
        gemm64_kernel<<<gg, 256, 0, stream>>>(xB, rel1, Wt1, y,
                                              initb, rel1, Wb1, z);
        fin_kernel<<<NN / 16, 256, 0, stream>>>(y, z, rp, cp, gnn_b + 64, xA);
    }

    // ---- query path ----
    query_kernel<<<1, 512, 0, stream>>>(query_emb, r_index, g_time_emb, g_time,
                                        g_lin_W, g_lin_b, query);
    xseq_kernel<<<(BB * HLENN * 128 + 255) / 256, 256, 0, stream>>>(xA, query, history_poi, hte, xseq);

    // ---- transformer (2 layers on [8,50,128]) ----
    for (int l = 0; l < 2; ++l) {
        qkv4_kernel<<<BB * HLENN / 4, 384, 0, stream>>>(xseq, tf_Wqkv + l * 128 * 384, qkvb);
        attn_kernel<<<BB * 2, 256, 0, stream>>>(qkvb, aout);
        addLN4_kernel<<<BB * HLENN / 4, 512, 0, stream>>>(aout, tf_Wo + l * 128 * 128,
                                                          tf_ln1 + l * 256, xseq);
        ffLN4_kernel<<<BB * HLENN / 4, 512, 0, stream>>>(xseq, tf_W1 + l * 128 * 512,
                                                         tf_b1 + l * 512, tf_W2 + l * 512 * 128,
                                                         tf_b2 + l * 128, tf_ln2 + l * 256, xseq);
    }

    // ---- scoring ----
    mean_kernel<<<(BB * 128 + 255) / 256, 256, 0, stream>>>(xseq, flab);
    score_kernel<<<BB * KK, 192, 0, stream>>>(xA, flab, t_index,
                                              mlp_W1, mlp_b1, mlp_W2, mlp_b2, (float*)d_out);
}